// Round 10
// baseline (124.497 us; speedup 1.0000x reference)
//
#include <hip/hip_runtime.h>
#include <cstdint>
#include <cstddef>

// Problem sizes (fixed by the reference)
#define MDIM 16384   // N_INPUT
#define CDIM 4096    // NUM_CENTERS
#define DDIM 256     // DIM
#define KDIM 512     // folded K elements; fp4 -> 256 bytes per row
#define KB   256     // row bytes (fp4)

typedef float f32x4  __attribute__((ext_vector_type(4)));
typedef int   i32x4v __attribute__((ext_vector_type(4)));
typedef int   i32x8v __attribute__((ext_vector_type(8)));

// e2m1 (OCP MXFP4) quantize, round-to-nearest: grid {0,.5,1,1.5,2,3,4,6}
__device__ __forceinline__ unsigned q4(float v) {
    unsigned s = (__builtin_bit_cast(unsigned, v) >> 31) << 3;
    float a = fabsf(v);
    unsigned c = (unsigned)(a >= 0.25f) + (a >= 0.75f) + (a >= 1.25f)
               + (a >= 1.75f) + (a >= 2.5f) + (a >= 3.5f) + (a >= 5.0f);
    return s | c;
}
__device__ __forceinline__ unsigned pack8(const float* v) {  // 8 vals -> 8 nibbles
    unsigned w = 0;
    #pragma unroll
    for (int i = 0; i < 8; ++i) w |= q4(v[i]) << (4 * i);
    return w;
}

// ---------------------------------------------------------------------------
// prep (fp4): A'[n] = [ x (256 fp4) | x^2/8 (256 fp4) ]       row = 256 B
//             B'[c] = [ -2*c*inv (256 fp4) | inv*8 (256 fp4) ]
//             constc[c] = sum_d c^2*inv (fp32).  Scales undone by MFMA E8M0.
// ---------------------------------------------------------------------------
__global__ __launch_bounds__(256) void prep(
    const float* __restrict__ x, const float* __restrict__ centers,
    const float* __restrict__ sigmas,
    unsigned char* __restrict__ Ap, unsigned char* __restrict__ Bp,
    float* __restrict__ constc, float* __restrict__ score) {
    int b = blockIdx.x, tid = threadIdx.x;
    if (b < 2048) {
        int idx8 = b * 256 + tid;                 // over MDIM*DDIM/8
        int n = idx8 >> 5, d8 = idx8 & 31;
        float v[8], v2[8];
        *(float4*)(v)     = ((const float4*)x)[idx8 * 2];
        *(float4*)(v + 4) = ((const float4*)x)[idx8 * 2 + 1];
        #pragma unroll
        for (int i = 0; i < 8; ++i) v2[i] = v[i] * v[i] * 0.125f;  // x^2/8
        *(unsigned*)(Ap + (size_t)n * KB + d8 * 4)       = pack8(v);
        *(unsigned*)(Ap + (size_t)n * KB + 128 + d8 * 4) = pack8(v2);
        if (idx8 < MDIM) score[idx8] = 0.0f;
    } else {
        int gid8 = (b - 2048) * 256 + tid;        // over CDIM*DDIM/8
        int c = gid8 >> 5, d8 = gid8 & 31;
        float cv[8], sv[8], cr[8], iv[8];
        *(float4*)(cv)     = ((const float4*)centers)[gid8 * 2];
        *(float4*)(cv + 4) = ((const float4*)centers)[gid8 * 2 + 1];
        *(float4*)(sv)     = ((const float4*)sigmas)[gid8 * 2];
        *(float4*)(sv + 4) = ((const float4*)sigmas)[gid8 * 2 + 1];
        float t = 0.0f;
        #pragma unroll
        for (int i = 0; i < 8; ++i) {
            float inv = 1.0f / (2.0f * sv[i] * sv[i]);
            cr[i] = -2.0f * cv[i] * inv;
            iv[i] = inv * 8.0f;                   // inv*8 (undone by 2^-3)
            t += cv[i] * cv[i] * inv;
        }
        *(unsigned*)(Bp + (size_t)c * KB + d8 * 4)       = pack8(cr);
        *(unsigned*)(Bp + (size_t)c * KB + 128 + d8 * 4) = pack8(iv);
        #pragma unroll
        for (int m = 16; m; m >>= 1) t += __shfl_xor(t, m, 64);  // 32-lane groups
        if ((tid & 31) == 0) constc[c] = t;
    }
}

// ---------------------------------------------------------------------------
// Fused MX-fp4 GEMM + exp + weighted C-reduction, double-buffered LDS.
// d2 = A' B'^T + constc ; score[m] += sum_n exp(-d2[m][n]) * w[n]
// R9: 256x128 tile, 4 waves of 64Mx128N, fp4 cbsz=blgp=4.
// BK=128 elems (64 B/row) per round -> buffers (16+8)KB x2 = 48 KB static.
// Ping-pong: stage(r+1) issued BEFORE compute(r); the round-end barrier's
// vmcnt drain then lands after a full compute phase -> stage latency hidden.
// 4-slot XOR swizzle: chunk g of row r at slot g^(r&3)^((r>>2)&3) ->
// ds_read_b128 2-way aliased (free, m136); staging fetch is slab-independent.
// Rounds 0,1 = x*cross (E8M0 1*1); rounds 2,3 = x^2*inv (2^3 * 2^-3).
// ---------------------------------------------------------------------------
__global__ __launch_bounds__(256, 2) void gemm_fused(
    const unsigned char* __restrict__ A, const unsigned char* __restrict__ B,
    const float* __restrict__ constc, const float* __restrict__ w,
    float* __restrict__ score) {

    __shared__ unsigned char As[2][256 * 64];   // 2 x 16 KB
    __shared__ unsigned char Bs[2][128 * 64];   // 2 x  8 KB

    const int tid  = threadIdx.x;
    const int wave = tid >> 6;
    const int lane = tid & 63;
    const int quad = lane >> 4;      // 0..3
    const int l16  = lane & 15;

    const int bm = blockIdx.y;       // 0..63   (M blocks of 256)
    const int bn = blockIdx.x;       // 0..31   (C blocks of 128)

    const int wave_m = wave * 64;    // wave's 64 M-rows

    f32x4 acc[4][8] = {};

    // epilogue constants prefetched; cjl = -log2e*constc folded to one fma.
    const float NEG_LOG2E = -1.4426950408889634f;
    float wj8[8], cjl8[8];
    #pragma unroll
    for (int j = 0; j < 8; ++j) {
        int ng = bn * 128 + j * 16 + l16;
        wj8[j]  = w[ng];
        cjl8[j] = NEG_LOG2E * constc[ng];
    }

    // staging: one global_load_lds(16B)/lane covers 1 KB = 16 rows x 64 B.
    // lane -> row-in-slab (lane>>2), slot (lane&3); fetch the XOR-swizzled
    // global chunk (slab-independent since slab*16 = 0 mod swizzle period).
    const int st_row = lane >> 2;                                  // 0..15
    const int st_k   = ((lane & 3) ^ ((lane >> 2) & 3) ^ ((lane >> 4) & 3)) * 16;

    const unsigned char* Abase = A + (size_t)(bm * 256) * KB;
    const unsigned char* Bbase = B + (size_t)(bn * 128) * KB;

    // fragment read slot: lane (l16,quad) needs 16B chunk 'quad' of its row,
    // stored at swizzled slot quad ^ (l16&3) ^ ((l16>>2)&3).
    const int s_off = (quad ^ (l16 & 3) ^ ((l16 >> 2) & 3)) * 16;

    #define STAGE(r, buf)                                                          \
        {                                                                          \
            const int koff = (r) * 64;                                             \
            _Pragma("unroll")                                                      \
            for (int c = 0; c < 4; ++c) {                                          \
                int slab = wave * 4 + c;            /* 0..15, 16 rows each */      \
                const unsigned char* ga =                                          \
                    Abase + (size_t)(slab * 16 + st_row) * KB + koff + st_k;       \
                __builtin_amdgcn_global_load_lds(                                  \
                    (const __attribute__((address_space(1))) void*)ga,             \
                    (__attribute__((address_space(3))) void*)(As[buf] + slab * 1024), \
                    16, 0, 0);                                                     \
            }                                                                      \
            _Pragma("unroll")                                                      \
            for (int c = 0; c < 2; ++c) {                                          \
                int slab = wave * 2 + c;            /* 0..7, 16 rows each */       \
                const unsigned char* gb =                                          \
                    Bbase + (size_t)(slab * 16 + st_row) * KB + koff + st_k;       \
                __builtin_amdgcn_global_load_lds(                                  \
                    (const __attribute__((address_space(1))) void*)gb,             \
                    (__attribute__((address_space(3))) void*)(Bs[buf] + slab * 1024), \
                    16, 0, 0);                                                     \
            }                                                                      \
        }

    STAGE(0, 0);
    __syncthreads();

    #pragma unroll
    for (int r = 0; r < 4; ++r) {
        if (r < 3) STAGE(r + 1, (r + 1) & 1);     // prefetch next round

        const int sA = (r >= 2) ? 0x82828282 : 0x7F7F7F7F;  // 2^3 : 2^0
        const int sB = (r >= 2) ? 0x7C7C7C7C : 0x7F7F7F7F;  // 2^-3 : 2^0
        const unsigned char* as = As[r & 1];
        const unsigned char* bs = Bs[r & 1];

        i32x8v af[4];
        #pragma unroll
        for (int i = 0; i < 4; ++i) {
            i32x4v lo = *(const i32x4v*)(as + (wave_m + i * 16 + l16) * 64 + s_off);
            af[i] = __builtin_shufflevector(lo, lo, 0, 1, 2, 3, -1, -1, -1, -1);
        }
        #pragma unroll
        for (int j = 0; j < 8; ++j) {
            i32x4v lo = *(const i32x4v*)(bs + (j * 16 + l16) * 64 + s_off);
            i32x8v bf = __builtin_shufflevector(lo, lo, 0, 1, 2, 3, -1, -1, -1, -1);
            #pragma unroll
            for (int i = 0; i < 4; ++i)
                acc[i][j] = __builtin_amdgcn_mfma_scale_f32_16x16x128_f8f6f4(
                    af[i], bf, acc[i][j],
                    4 /*cbsz: fp4 e2m1*/, 4 /*blgp: fp4 e2m1*/,
                    0, sA, 0, sB);
        }
        __syncthreads();   // drains stage(r+1) vmcnt + protects buf[r&1]
    }
    #undef STAGE

    // Epilogue: rowsum[i][r] += exp2(d2*(-log2e) + cjl) * wj
    // C/D layout (16x16 shapes): col = l16 (=n), row = quad*4 + reg (=m).
    float rowsum[4][4];
    #pragma unroll
    for (int i = 0; i < 4; ++i)
        #pragma unroll
        for (int r = 0; r < 4; ++r) rowsum[i][r] = 0.0f;

    #pragma unroll
    for (int j = 0; j < 8; ++j) {
        float wj  = wj8[j];
        float cjl = cjl8[j];
        #pragma unroll
        for (int i = 0; i < 4; ++i)
            #pragma unroll
            for (int r = 0; r < 4; ++r)
                rowsum[i][r] += exp2f(fmaf(acc[i][j][r], NEG_LOG2E, cjl)) * wj;
    }

    #pragma unroll
    for (int mask = 1; mask < 16; mask <<= 1)
        #pragma unroll
        for (int i = 0; i < 4; ++i)
            #pragma unroll
            for (int r = 0; r < 4; ++r)
                rowsum[i][r] += __shfl_xor(rowsum[i][r], mask, 64);

    if (l16 == 0) {
        #pragma unroll
        for (int i = 0; i < 4; ++i)
            #pragma unroll
            for (int r = 0; r < 4; ++r) {
                int mg = bm * 256 + wave_m + i * 16 + quad * 4 + r;
                atomicAdd(&score[mg], rowsum[i][r]);
            }
    }
}

// ---------------------------------------------------------------------------
// finalize: out[n] = sigmoid(score[n] + b)
// ---------------------------------------------------------------------------
__global__ void finalize(const float* __restrict__ score,
                         const float* __restrict__ b,
                         float* __restrict__ out) {
    int n = blockIdx.x * 256 + threadIdx.x;
    if (n < MDIM) {
        float s = score[n] + b[0];
        out[n] = 1.0f / (1.0f + exp2f(-1.4426950408889634f * s));
    }
}

extern "C" void kernel_launch(void* const* d_in, const int* in_sizes, int n_in,
                              void* d_out, int out_size, void* d_ws, size_t ws_size,
                              hipStream_t stream) {
    const float* x       = (const float*)d_in[0];
    const float* centers = (const float*)d_in[1];
    const float* sigmas  = (const float*)d_in[2];
    const float* w_lin   = (const float*)d_in[3];
    const float* b_lin   = (const float*)d_in[4];
    float* out = (float*)d_out;

    char* ws = (char*)d_ws;
    unsigned char* Ap = (unsigned char*)ws;                       // 4 MB
    unsigned char* Bp = (unsigned char*)(ws + (size_t)MDIM * KB); // 1 MB
    float* cc    = (float*)(ws + (size_t)MDIM * KB + (size_t)CDIM * KB); // 16 KB
    float* score = (float*)((char*)cc + CDIM * sizeof(float));    // 64 KB

    prep<<<dim3(2048 + 512), dim3(256), 0, stream>>>(
        x, centers, sigmas, Ap, Bp, cc, score);
    gemm_fused<<<dim3(CDIM / 128, MDIM / 256), dim3(256), 0, stream>>>(
        Ap, Bp, cc, w_lin, score);
    finalize<<<dim3((MDIM + 255) / 256), dim3(256), 0, stream>>>(score, b_lin, out);
}

// Round 11
// 117.102 us; speedup vs baseline: 1.0631x; 1.0631x over previous
//
#include <hip/hip_runtime.h>
#include <cstdint>
#include <cstddef>

// Problem sizes (fixed by the reference)
#define MDIM 16384   // N_INPUT
#define CDIM 4096    // NUM_CENTERS
#define DDIM 256     // DIM
#define KDIM 512     // folded K elements; fp4 -> 256 bytes per row
#define KB   256     // row bytes (fp4)

typedef float f32x4  __attribute__((ext_vector_type(4)));
typedef int   i32x4v __attribute__((ext_vector_type(4)));
typedef int   i32x8v __attribute__((ext_vector_type(8)));

// e2m1 (OCP MXFP4) quantize, round-to-nearest: grid {0,.5,1,1.5,2,3,4,6}
__device__ __forceinline__ unsigned q4(float v) {
    unsigned s = (__builtin_bit_cast(unsigned, v) >> 31) << 3;
    float a = fabsf(v);
    unsigned c = (unsigned)(a >= 0.25f) + (a >= 0.75f) + (a >= 1.25f)
               + (a >= 1.75f) + (a >= 2.5f) + (a >= 3.5f) + (a >= 5.0f);
    return s | c;
}
__device__ __forceinline__ unsigned pack8(const float* v) {  // 8 vals -> 8 nibbles
    unsigned w = 0;
    #pragma unroll
    for (int i = 0; i < 8; ++i) w |= q4(v[i]) << (4 * i);
    return w;
}

// ---------------------------------------------------------------------------
// prep (fp4): A'[n] = [ x (256 fp4) | x^2/8 (256 fp4) ]       row = 256 B
//             B'[c] = [ -2*c*inv (256 fp4) | inv*8 (256 fp4) ]
//             constc[c] = sum_d c^2*inv (fp32).  Scales undone by MFMA E8M0.
// ---------------------------------------------------------------------------
__global__ __launch_bounds__(256) void prep(
    const float* __restrict__ x, const float* __restrict__ centers,
    const float* __restrict__ sigmas,
    unsigned char* __restrict__ Ap, unsigned char* __restrict__ Bp,
    float* __restrict__ constc, float* __restrict__ score) {
    int b = blockIdx.x, tid = threadIdx.x;
    if (b < 2048) {
        int idx8 = b * 256 + tid;                 // over MDIM*DDIM/8
        int n = idx8 >> 5, d8 = idx8 & 31;
        float v[8], v2[8];
        *(float4*)(v)     = ((const float4*)x)[idx8 * 2];
        *(float4*)(v + 4) = ((const float4*)x)[idx8 * 2 + 1];
        #pragma unroll
        for (int i = 0; i < 8; ++i) v2[i] = v[i] * v[i] * 0.125f;  // x^2/8
        *(unsigned*)(Ap + (size_t)n * KB + d8 * 4)       = pack8(v);
        *(unsigned*)(Ap + (size_t)n * KB + 128 + d8 * 4) = pack8(v2);
        if (idx8 < MDIM) score[idx8] = 0.0f;
    } else {
        int gid8 = (b - 2048) * 256 + tid;        // over CDIM*DDIM/8
        int c = gid8 >> 5, d8 = gid8 & 31;
        float cv[8], sv[8], cr[8], iv[8];
        *(float4*)(cv)     = ((const float4*)centers)[gid8 * 2];
        *(float4*)(cv + 4) = ((const float4*)centers)[gid8 * 2 + 1];
        *(float4*)(sv)     = ((const float4*)sigmas)[gid8 * 2];
        *(float4*)(sv + 4) = ((const float4*)sigmas)[gid8 * 2 + 1];
        float t = 0.0f;
        #pragma unroll
        for (int i = 0; i < 8; ++i) {
            float inv = 1.0f / (2.0f * sv[i] * sv[i]);
            cr[i] = -2.0f * cv[i] * inv;
            iv[i] = inv * 8.0f;                   // inv*8 (undone by 2^-3)
            t += cv[i] * cv[i] * inv;
        }
        *(unsigned*)(Bp + (size_t)c * KB + d8 * 4)       = pack8(cr);
        *(unsigned*)(Bp + (size_t)c * KB + 128 + d8 * 4) = pack8(iv);
        #pragma unroll
        for (int m = 16; m; m >>= 1) t += __shfl_xor(t, m, 64);  // 32-lane groups
        if ((tid & 31) == 0) constc[c] = t;
    }
}

// ---------------------------------------------------------------------------
// Fused MX-fp4 GEMM + exp + weighted C-reduction.
// d2 = A' B'^T + constc ; score[m] += sum_n exp(-d2[m][n]) * w[n]
// R10: 128x128 tile (wave = 32M x 128N) -> acc[2][8] = 64 acc regs,
// ~150 unified regs/wave -> 3 waves/SIMD (launch_bounds(256,3)); LDS 32 KB
// -> 3 blocks/CU co-resident (12 waves/CU vs R8's 8). R8's register cap
// (acc[4][8]=128 AGPR -> 256 unified -> 2 waves/SIMD) was the occupancy
// binding constraint. Round geometry byte-identical to R8: BK=256 elems =
// 128 B/row, 8x16B slots, XOR swizzle chunk g of row r at slot g^(r&7)
// (0 conflicts), two K=128 windows per round, per-round E8M0 scales.
// Single-buffered (R9 dbuf regressed).
// ---------------------------------------------------------------------------
__global__ __launch_bounds__(256, 3) void gemm_fused(
    const unsigned char* __restrict__ A, const unsigned char* __restrict__ B,
    const float* __restrict__ constc, const float* __restrict__ w,
    float* __restrict__ score) {

    __shared__ unsigned char As[128 * 128];   // 16 KB
    __shared__ unsigned char Bs[128 * 128];   // 16 KB

    const int tid  = threadIdx.x;
    const int wave = tid >> 6;
    const int lane = tid & 63;
    const int quad = lane >> 4;      // 0..3
    const int l16  = lane & 15;

    const int bm = blockIdx.y;       // 0..127  (M blocks of 128)
    const int bn = blockIdx.x;       // 0..31   (C blocks of 128)

    const int wave_m = wave * 32;    // wave's 32 M-rows

    f32x4 acc[2][8] = {};

    // epilogue constants prefetched; cjl = -log2e*constc folded to one fma.
    const float NEG_LOG2E = -1.4426950408889634f;
    float wj8[8], cjl8[8];
    #pragma unroll
    for (int j = 0; j < 8; ++j) {
        int ng = bn * 128 + j * 16 + l16;
        wj8[j]  = w[ng];
        cjl8[j] = NEG_LOG2E * constc[ng];
    }

    // staging: one global_load_lds(16B)/lane stages 1024 B = 8 rows x 128 B.
    // lane -> row (lane>>3), slot (lane&7); fetch XOR-swizzled global chunk.
    const int st_row = lane >> 3;                     // 0..7
    const int st_k   = ((lane & 7) ^ st_row) * 16;    // swizzled global byte off

    const unsigned char* Abase = A + (size_t)(bm * 128) * KB;
    const unsigned char* Bbase = B + (size_t)(bn * 128) * KB;

    const int rsw = l16 & 7;

    #pragma unroll
    for (int k0 = 0; k0 < 2; ++k0) {              // 2 rounds of 128 B (=256 elems)
        const int sA = k0 ? 0x82828282 : 0x7F7F7F7F;   // 2^3 : 2^0
        const int sB = k0 ? 0x7C7C7C7C : 0x7F7F7F7F;   // 2^-3 : 2^0
        #pragma unroll
        for (int c = 0; c < 4; ++c) {             // A: 16 slabs of 8 rows
            int slab = wave * 4 + c;              // 0..15
            const unsigned char* ga = Abase + (size_t)(slab * 8 + st_row) * KB + k0 * 128 + st_k;
            __builtin_amdgcn_global_load_lds(
                (const __attribute__((address_space(1))) void*)ga,
                (__attribute__((address_space(3))) void*)(As + slab * 1024), 16, 0, 0);
        }
        #pragma unroll
        for (int c = 0; c < 4; ++c) {             // B: 16 slabs of 8 rows
            int slab = wave * 4 + c;              // 0..15
            const unsigned char* gb = Bbase + (size_t)(slab * 8 + st_row) * KB + k0 * 128 + st_k;
            __builtin_amdgcn_global_load_lds(
                (const __attribute__((address_space(1))) void*)gb,
                (__attribute__((address_space(3))) void*)(Bs + slab * 1024), 16, 0, 0);
        }
        __syncthreads();

        #pragma unroll
        for (int kh = 0; kh < 2; ++kh) {          // two K=128 MFMA windows
            const int sl = ((kh * 4 + quad) ^ rsw) * 16;
            i32x8v af[2];
            #pragma unroll
            for (int i = 0; i < 2; ++i) {
                i32x4v lo = *(const i32x4v*)(As + (wave_m + i * 16 + l16) * 128 + sl);
                af[i] = __builtin_shufflevector(lo, lo, 0, 1, 2, 3, -1, -1, -1, -1);
            }
            #pragma unroll
            for (int j = 0; j < 8; ++j) {
                i32x4v lo = *(const i32x4v*)(Bs + (j * 16 + l16) * 128 + sl);
                i32x8v bf = __builtin_shufflevector(lo, lo, 0, 1, 2, 3, -1, -1, -1, -1);
                #pragma unroll
                for (int i = 0; i < 2; ++i)
                    acc[i][j] = __builtin_amdgcn_mfma_scale_f32_16x16x128_f8f6f4(
                        af[i], bf, acc[i][j],
                        4 /*cbsz: fp4 e2m1*/, 4 /*blgp: fp4 e2m1*/,
                        0, sA, 0, sB);
            }
        }
        __syncthreads();
    }

    // Epilogue: rowsum[i][r] += exp2(d2*(-log2e) + cjl) * wj
    // C/D layout (16x16 shapes): col = l16 (=n), row = quad*4 + reg (=m).
    float rowsum[2][4];
    #pragma unroll
    for (int i = 0; i < 2; ++i)
        #pragma unroll
        for (int r = 0; r < 4; ++r) rowsum[i][r] = 0.0f;

    #pragma unroll
    for (int j = 0; j < 8; ++j) {
        float wj  = wj8[j];
        float cjl = cjl8[j];
        #pragma unroll
        for (int i = 0; i < 2; ++i)
            #pragma unroll
            for (int r = 0; r < 4; ++r)
                rowsum[i][r] += exp2f(fmaf(acc[i][j][r], NEG_LOG2E, cjl)) * wj;
    }

    #pragma unroll
    for (int mask = 1; mask < 16; mask <<= 1)
        #pragma unroll
        for (int i = 0; i < 2; ++i)
            #pragma unroll
            for (int r = 0; r < 4; ++r)
                rowsum[i][r] += __shfl_xor(rowsum[i][r], mask, 64);

    if (l16 == 0) {
        #pragma unroll
        for (int i = 0; i < 2; ++i)
            #pragma unroll
            for (int r = 0; r < 4; ++r) {
                int mg = bm * 128 + wave_m + i * 16 + quad * 4 + r;
                atomicAdd(&score[mg], rowsum[i][r]);
            }
    }
}

// ---------------------------------------------------------------------------
// finalize: out[n] = sigmoid(score[n] + b)
// ---------------------------------------------------------------------------
__global__ void finalize(const float* __restrict__ score,
                         const float* __restrict__ b,
                         float* __restrict__ out) {
    int n = blockIdx.x * 256 + threadIdx.x;
    if (n < MDIM) {
        float s = score[n] + b[0];
        out[n] = 1.0f / (1.0f + exp2f(-1.4426950408889634f * s));
    }
}

extern "C" void kernel_launch(void* const* d_in, const int* in_sizes, int n_in,
                              void* d_out, int out_size, void* d_ws, size_t ws_size,
                              hipStream_t stream) {
    const float* x       = (const float*)d_in[0];
    const float* centers = (const float*)d_in[1];
    const float* sigmas  = (const float*)d_in[2];
    const float* w_lin   = (const float*)d_in[3];
    const float* b_lin   = (const float*)d_in[4];
    float* out = (float*)d_out;

    char* ws = (char*)d_ws;
    unsigned char* Ap = (unsigned char*)ws;                       // 4 MB
    unsigned char* Bp = (unsigned char*)(ws + (size_t)MDIM * KB); // 1 MB
    float* cc    = (float*)(ws + (size_t)MDIM * KB + (size_t)CDIM * KB); // 16 KB
    float* score = (float*)((char*)cc + CDIM * sizeof(float));    // 64 KB

    prep<<<dim3(2048 + 512), dim3(256), 0, stream>>>(
        x, centers, sigmas, Ap, Bp, cc, score);
    gemm_fused<<<dim3(CDIM / 128, MDIM / 128), dim3(256), 0, stream>>>(
        Ap, Bp, cc, w_lin, score);
    finalize<<<dim3((MDIM + 255) / 256), dim3(256), 0, stream>>>(score, b_lin, out);
}